// Round 1
// 255.153 us; speedup vs baseline: 1.0557x; 1.0557x over previous
//
#include <hip/hip_runtime.h>
#include <stdint.h>

#define B_      32
#define T_IN_   512
#define N_      543
#define C_      3
#define NEW_T_  426     // int(512/1.2)
#define JF_     53      // max(1, 426//8)
#define NC_     (N_*C_)             // 1629
#define XOUT_   (B_*NEW_T_*NC_)     // 22206528
#define NFR_    (B_*NEW_T_)         // 13632 frames
#define GPF_    408                 // groups per frame: ceil(1629/4)
#define FPB_    6                   // frames per block strip
#define NTB_    71                  // 426 / 6, exact

#define MODE_INT   0
#define MODE_BYTE  1
#define MODE_FLOAT 2

// 16-byte vector, 4-byte alignment (frame stride 1629 floats is odd).
typedef float f4u __attribute__((vector_size(16), aligned(4)));

__device__ __forceinline__ bool read_flag(const void* p, int mode, int idx) {
    if (mode == MODE_BYTE)  return ((const uint8_t*)p)[idx] != 0;
    if (mode == MODE_FLOAT) return ((const float*)p)[idx]   != 0.0f;
    return ((const int*)p)[idx] != 0;
}

// One block per batch. Builds per-(b,t): 4 frame indices + 4 weights for pd[b,t],
// jitter value (0 at t=0), and writes the mask output.
// Kept frames get F=(i0,i0+1,i0,i0+1), W=(1-w,w,0,0): main skips the zero-weight
// taps via a wave-uniform branch (all lanes of a main wave share the frame).
__global__ __launch_bounds__(512) void prep_kernel(
    const void* __restrict__ maskp,
    const void* __restrict__ keepp,
    const float* __restrict__ bjit,
    float* __restrict__ out_mask,
    int4*  __restrict__ wsF,
    float4* __restrict__ wsW,
    float* __restrict__ wsJ)
{
    const int b = blockIdx.x;
    const int tid = threadIdx.x;

    __shared__ int flags[6];
    __shared__ int s_mode_mask, s_mode_keep;
    if (tid < 6) flags[tid] = 0;
    __syncthreads();
    if (tid < 64) {
        uint32_t vm = ((const uint32_t*)maskp)[tid];
        uint32_t vk = ((const uint32_t*)keepp)[tid];
        if (vm == 0x3F800000u)      atomicOr(&flags[2], 1);
        else if (vm > 1u)           atomicOr(&flags[1], 1);
        if (vk == 0x3F800000u)      atomicOr(&flags[5], 1);
        else if (vk > 1u)           atomicOr(&flags[4], 1);
    }
    __syncthreads();
    if (tid == 0) {
        s_mode_mask = flags[2] ? MODE_FLOAT : (flags[1] ? MODE_BYTE : MODE_INT);
        s_mode_keep = flags[5] ? MODE_FLOAT : (flags[4] ? MODE_BYTE : MODE_INT);
    }
    __syncthreads();
    const int mmode = s_mode_mask, kmode = s_mode_keep;

    __shared__ int sk[512];
    __shared__ int ps[512];
    __shared__ int kept[NEW_T_];

    int kv = 0;
    if (tid < NEW_T_) kv = read_flag(keepp, kmode, b*NEW_T_ + tid) ? 1 : 0;
    sk[tid] = (tid < NEW_T_) ? kv : 0;
    ps[tid] = sk[tid];
    __syncthreads();
    for (int off = 1; off < 512; off <<= 1) {
        int v = (tid >= off) ? ps[tid - off] : 0;
        __syncthreads();
        ps[tid] += v;
        __syncthreads();
    }
    const int K = ps[NEW_T_ - 1];
    if (tid < NEW_T_ && kv) kept[ps[tid] - 1] = tid;
    __syncthreads();

    if (tid < NEW_T_) {
        const int t = tid;
        const float RATX = (float)(511.0 / 425.0);
        float st = (float)t * RATX;
        int i0 = (int)floorf(st);
        if (i0 < 0) i0 = 0; if (i0 > T_IN_ - 2) i0 = T_IN_ - 2;
        float w = st - (float)i0;

        int4 F; float4 W;
        if (kv) {
            F = make_int4(i0, i0 + 1, i0, i0 + 1);
            W = make_float4(1.0f - w, w, 0.0f, 0.0f);
        } else {
            float s = ((float)t * (float)(K - 1)) / 425.0f;
            int r0 = (int)floorf(s);
            if (r0 < 0) r0 = 0; if (r0 > K - 2) r0 = K - 2;
            float f = s - (float)r0;
            int j0 = kept[r0], j1 = kept[r0 + 1];
            float s0 = (float)j0 * RATX;
            int a0 = (int)floorf(s0);
            if (a0 < 0) a0 = 0; if (a0 > T_IN_ - 2) a0 = T_IN_ - 2;
            float w0 = s0 - (float)a0;
            float s1 = (float)j1 * RATX;
            int a1 = (int)floorf(s1);
            if (a1 < 0) a1 = 0; if (a1 > T_IN_ - 2) a1 = T_IN_ - 2;
            float w1 = s1 - (float)a1;
            F = make_int4(a0, a0 + 1, a1, a1 + 1);
            W = make_float4((1.0f - f) * (1.0f - w0), (1.0f - f) * w0,
                            f * (1.0f - w1),          f * w1);
        }
        const int bt = b * NEW_T_ + t;
        wsF[bt] = F;
        wsW[bt] = W;

        const float RATJ = (float)(52.0 / 425.0);
        float sj = (float)t * RATJ;
        int ji = (int)floorf(sj);
        if (ji < 0) ji = 0; if (ji > JF_ - 2) ji = JF_ - 2;
        float jf = sj - (float)ji;
        float b0 = bjit[b*JF_ + ji]     * 0.02f;
        float b1 = bjit[b*JF_ + ji + 1] * 0.02f;
        float jv = b0 * (1.0f - jf) + b1 * jf;
        if (t == 0) jv = 0.0f;
        wsJ[bt] = jv;

        float mn = (float)t * (float)(512.0 / 426.0);
        int nidx = (int)floorf(mn);
        if (nidx > T_IN_ - 1) nidx = T_IN_ - 1;
        bool mo = read_flag(maskp, mmode, b*T_IN_ + nidx) && (kv != 0);
        out_mask[bt] = mo ? 1.0f : 0.0f;
    }
}

// One block per (batch b, strip of FPB_=6 consecutive frames).
// Thread j owns spatial column e0=4j across the strip:
//  - ap (prev-frame interp) carried in registers frame-to-frame: Q-loads gone
//  - spat loaded once per thread
//  - bt is block-uniform -> wsF/wsW/wsJ are scalar s_loads (zero VMEM slots)
//  - kept/dropped branch is wave-uniform -> T2/T3 loads skipped for ~90% frames
// VMEM thread-ops per output group drop ~16 -> ~4.5; HBM bytes unchanged.
__global__ __launch_bounds__(448) __attribute__((amdgpu_waves_per_eu(3, 8)))
void main_kernel(
    const float* __restrict__ x,
    const float* __restrict__ noise,
    const float* __restrict__ spat,
    const int4*  __restrict__ wsF,
    const float4* __restrict__ wsW,
    const float* __restrict__ wsJ,
    float* __restrict__ out)
{
    const int j = threadIdx.x;
    if (j >= GPF_) return;                       // no barriers below; safe
    const int b  = blockIdx.y;
    const int t0 = blockIdx.x * FPB_;

    uint32_t e0 = (uint32_t)j * 4u;
    if (e0 > (uint32_t)(NC_ - 4)) e0 = (uint32_t)(NC_ - 4);   // tail overlap writes identical values

    const float* __restrict__ xb = x + (size_t)b * (T_IN_ * NC_);

    // per-thread invariants
    const f4u sp = *(const f4u*)(spat + (size_t)b * NC_ + e0);

    // prologue: ap = interp of frame t0-1 (clamped; t=0 has jitter 0 so value is moot)
    f4u ap;
    {
        const int pbt = b * NEW_T_ + (t0 ? t0 - 1 : 0);
        const int4   Fp = wsF[pbt];
        const float4 Wp = wsW[pbt];
        f4u q0 = *(const f4u*)(xb + (uint32_t)Fp.x * NC_ + e0);
        f4u q1 = *(const f4u*)(xb + (uint32_t)Fp.y * NC_ + e0);
        ap = Wp.x * q0 + Wp.y * q1;
        if (Wp.z != 0.0f || Wp.w != 0.0f) {      // wave-uniform (scalar W)
            f4u q2 = *(const f4u*)(xb + (uint32_t)Fp.z * NC_ + e0);
            f4u q3 = *(const f4u*)(xb + (uint32_t)Fp.w * NC_ + e0);
            ap += Wp.z * q2 + Wp.w * q3;
        }
    }

    #pragma unroll
    for (int i = 0; i < FPB_; ++i) {
        const int bt = b * NEW_T_ + t0 + i;      // block-uniform -> scalar loads
        const int4   F = wsF[bt];
        const float4 W = wsW[bt];
        const float jv = wsJ[bt];

        // noise is read-once: keep it out of L2 (leave L2 for x rows)
        f4u nz = __builtin_nontemporal_load((const f4u*)(noise + (size_t)bt * NC_ + e0));

        f4u v0 = *(const f4u*)(xb + (uint32_t)F.x * NC_ + e0);
        f4u v1 = *(const f4u*)(xb + (uint32_t)F.y * NC_ + e0);
        f4u a  = W.x * v0 + W.y * v1;
        if (W.z != 0.0f || W.w != 0.0f) {        // wave-uniform: dropped frames only (~10%)
            f4u v2 = *(const f4u*)(xb + (uint32_t)F.z * NC_ + e0);
            f4u v3 = *(const f4u*)(xb + (uint32_t)F.w * NC_ + e0);
            a += W.z * v2 + W.w * v3;            // skipped terms are exactly 0*x
        }

        f4u r = a + (a - ap) * jv + nz * 0.01f + sp * 0.005f;
        __builtin_nontemporal_store(r, (f4u*)(out + (size_t)bt * NC_ + e0));
        ap = a;                                   // register-carried: replaces 4 Q-loads
    }
}

extern "C" void kernel_launch(void* const* d_in, const int* in_sizes, int n_in,
                              void* d_out, int out_size, void* d_ws, size_t ws_size,
                              hipStream_t stream) {
    const float* x    = (const float*)d_in[0];
    const void*  mask = d_in[1];
    const void*  keep = d_in[2];
    const float* bjit = (const float*)d_in[3];
    const float* noise = (const float*)d_in[4];
    const float* spat  = (const float*)d_in[5];
    float* out = (float*)d_out;

    char* ws = (char*)d_ws;
    int4*   wsF = (int4*)ws;                           // 218112 B
    float4* wsW = (float4*)(ws + 218112);              // 218112 B
    float*  wsJ = (float*)(ws + 436224);               // 54528 B

    prep_kernel<<<B_, 512, 0, stream>>>(mask, keep, bjit,
                                        out + XOUT_, wsF, wsW, wsJ);
    main_kernel<<<dim3(NTB_, B_), 448, 0, stream>>>(x, noise, spat, wsF, wsW, wsJ, out);
}

// Round 2
// 251.119 us; speedup vs baseline: 1.0727x; 1.0161x over previous
//
#include <hip/hip_runtime.h>
#include <stdint.h>

#define B_      32
#define T_IN_   512
#define N_      543
#define C_      3
#define NEW_T_  426     // int(512/1.2)
#define JF_     53      // max(1, 426//8)
#define NC_     (N_*C_)             // 1629
#define XOUT_   (B_*NEW_T_*NC_)     // 22206528
#define NFR_    (B_*NEW_T_)         // 13632 frames
#define GPF_    408                 // groups per frame: ceil(1629/4)
#define FPB_    6                   // frames per block strip
#define NTB_    71                  // 426 / 6, exact

#define MODE_INT   0
#define MODE_BYTE  1
#define MODE_FLOAT 2

// 16-byte vector, 4-byte alignment (frame stride 1629 floats is odd).
typedef float f4u __attribute__((vector_size(16), aligned(4)));

__device__ __forceinline__ bool read_flag(const void* p, int mode, int idx) {
    if (mode == MODE_BYTE)  return ((const uint8_t*)p)[idx] != 0;
    if (mode == MODE_FLOAT) return ((const float*)p)[idx]   != 0.0f;
    return ((const int*)p)[idx] != 0;
}

// One block per batch. Builds per-(b,t): 4 frame indices + 4 weights for pd[b,t],
// jitter value (0 at t=0), and writes the mask output.
// Kept frames get F=(i0,i0+1,i0,i0+1), W=(1-w,w,0,0): main skips the zero-weight
// taps via a wave-uniform branch (all lanes of a main wave share the frame).
__global__ __launch_bounds__(512) void prep_kernel(
    const void* __restrict__ maskp,
    const void* __restrict__ keepp,
    const float* __restrict__ bjit,
    float* __restrict__ out_mask,
    int4*  __restrict__ wsF,
    float4* __restrict__ wsW,
    float* __restrict__ wsJ)
{
    const int b = blockIdx.x;
    const int tid = threadIdx.x;

    __shared__ int flags[6];
    __shared__ int s_mode_mask, s_mode_keep;
    if (tid < 6) flags[tid] = 0;
    __syncthreads();
    if (tid < 64) {
        uint32_t vm = ((const uint32_t*)maskp)[tid];
        uint32_t vk = ((const uint32_t*)keepp)[tid];
        if (vm == 0x3F800000u)      atomicOr(&flags[2], 1);
        else if (vm > 1u)           atomicOr(&flags[1], 1);
        if (vk == 0x3F800000u)      atomicOr(&flags[5], 1);
        else if (vk > 1u)           atomicOr(&flags[4], 1);
    }
    __syncthreads();
    if (tid == 0) {
        s_mode_mask = flags[2] ? MODE_FLOAT : (flags[1] ? MODE_BYTE : MODE_INT);
        s_mode_keep = flags[5] ? MODE_FLOAT : (flags[4] ? MODE_BYTE : MODE_INT);
    }
    __syncthreads();
    const int mmode = s_mode_mask, kmode = s_mode_keep;

    __shared__ int sk[512];
    __shared__ int ps[512];
    __shared__ int kept[NEW_T_];

    int kv = 0;
    if (tid < NEW_T_) kv = read_flag(keepp, kmode, b*NEW_T_ + tid) ? 1 : 0;
    sk[tid] = (tid < NEW_T_) ? kv : 0;
    ps[tid] = sk[tid];
    __syncthreads();
    for (int off = 1; off < 512; off <<= 1) {
        int v = (tid >= off) ? ps[tid - off] : 0;
        __syncthreads();
        ps[tid] += v;
        __syncthreads();
    }
    const int K = ps[NEW_T_ - 1];
    if (tid < NEW_T_ && kv) kept[ps[tid] - 1] = tid;
    __syncthreads();

    if (tid < NEW_T_) {
        const int t = tid;
        const float RATX = (float)(511.0 / 425.0);
        float st = (float)t * RATX;
        int i0 = (int)floorf(st);
        if (i0 < 0) i0 = 0; if (i0 > T_IN_ - 2) i0 = T_IN_ - 2;
        float w = st - (float)i0;

        int4 F; float4 W;
        if (kv) {
            F = make_int4(i0, i0 + 1, i0, i0 + 1);
            W = make_float4(1.0f - w, w, 0.0f, 0.0f);
        } else {
            float s = ((float)t * (float)(K - 1)) / 425.0f;
            int r0 = (int)floorf(s);
            if (r0 < 0) r0 = 0; if (r0 > K - 2) r0 = K - 2;
            float f = s - (float)r0;
            int j0 = kept[r0], j1 = kept[r0 + 1];
            float s0 = (float)j0 * RATX;
            int a0 = (int)floorf(s0);
            if (a0 < 0) a0 = 0; if (a0 > T_IN_ - 2) a0 = T_IN_ - 2;
            float w0 = s0 - (float)a0;
            float s1 = (float)j1 * RATX;
            int a1 = (int)floorf(s1);
            if (a1 < 0) a1 = 0; if (a1 > T_IN_ - 2) a1 = T_IN_ - 2;
            float w1 = s1 - (float)a1;
            F = make_int4(a0, a0 + 1, a1, a1 + 1);
            W = make_float4((1.0f - f) * (1.0f - w0), (1.0f - f) * w0,
                            f * (1.0f - w1),          f * w1);
        }
        const int bt = b * NEW_T_ + t;
        wsF[bt] = F;
        wsW[bt] = W;

        const float RATJ = (float)(52.0 / 425.0);
        float sj = (float)t * RATJ;
        int ji = (int)floorf(sj);
        if (ji < 0) ji = 0; if (ji > JF_ - 2) ji = JF_ - 2;
        float jf = sj - (float)ji;
        float b0 = bjit[b*JF_ + ji]     * 0.02f;
        float b1 = bjit[b*JF_ + ji + 1] * 0.02f;
        float jv = b0 * (1.0f - jf) + b1 * jf;
        if (t == 0) jv = 0.0f;
        wsJ[bt] = jv;

        float mn = (float)t * (float)(512.0 / 426.0);
        int nidx = (int)floorf(mn);
        if (nidx > T_IN_ - 1) nidx = T_IN_ - 1;
        bool mo = read_flag(maskp, mmode, b*T_IN_ + nidx) && (kv != 0);
        out_mask[bt] = mo ? 1.0f : 0.0f;
    }
}

// One block per (batch b, strip of FPB_=6 consecutive frames).
// Thread j owns spatial column e0=4j across the strip.
// R1 structure kept: scalar ws loads, register-carried ap, wave-uniform skip of
// zero-weight taps. NEW: explicit phase split — ALL primary vector loads (6x v0,
// 6x v1, 6x nz, prologue q0/q1, sp = 15 x 16B) issued back-to-back before any
// use, so each wave keeps ~15 KB in flight instead of ~3 (R1's VGPR=20 meant the
// compiler serialized every frame into a full memory-latency round trip).
// Rare (~10%) dropped-frame v2/v3 taps load late in phase C (L2-hot).
__global__ __launch_bounds__(448) __attribute__((amdgpu_waves_per_eu(4, 8)))
void main_kernel(
    const float* __restrict__ x,
    const float* __restrict__ noise,
    const float* __restrict__ spat,
    const int4*  __restrict__ wsF,
    const float4* __restrict__ wsW,
    const float* __restrict__ wsJ,
    float* __restrict__ out)
{
    const int j = threadIdx.x;
    if (j >= GPF_) return;                       // no barriers below; safe
    const int b  = blockIdx.y;
    const int t0 = blockIdx.x * FPB_;

    uint32_t e0 = (uint32_t)j * 4u;
    if (e0 > (uint32_t)(NC_ - 4)) e0 = (uint32_t)(NC_ - 4);   // tail overlap writes identical values

    const float* __restrict__ xb = x + (size_t)b * (T_IN_ * NC_);
    const int bt0 = b * NEW_T_ + t0;

    // ---- Phase A: block-uniform ws loads (scalar s_loads) ----
    int4   F[FPB_]; float4 W[FPB_]; float jv[FPB_];
    #pragma unroll
    for (int i = 0; i < FPB_; ++i) {
        F[i]  = wsF[bt0 + i];
        W[i]  = wsW[bt0 + i];
        jv[i] = wsJ[bt0 + i];
    }
    const int pbt = b * NEW_T_ + (t0 ? t0 - 1 : 0);
    const int4   Fp = wsF[pbt];
    const float4 Wp = wsW[pbt];

    // ---- Phase B: issue every primary load back-to-back (nothing consumed yet) ----
    f4u v0[FPB_], v1[FPB_], nz[FPB_];
    #pragma unroll
    for (int i = 0; i < FPB_; ++i) {
        v0[i] = *(const f4u*)(xb + (uint32_t)F[i].x * NC_ + e0);
        v1[i] = *(const f4u*)(xb + (uint32_t)F[i].y * NC_ + e0);
    }
    f4u q0 = *(const f4u*)(xb + (uint32_t)Fp.x * NC_ + e0);
    f4u q1 = *(const f4u*)(xb + (uint32_t)Fp.y * NC_ + e0);
    #pragma unroll
    for (int i = 0; i < FPB_; ++i)
        nz[i] = __builtin_nontemporal_load((const f4u*)(noise + (size_t)(bt0 + i) * NC_ + e0));
    const f4u sp = *(const f4u*)(spat + (size_t)b * NC_ + e0);

    // ---- prologue combine: ap = interp of frame t0-1 (t=0 has jitter 0) ----
    f4u ap = Wp.x * q0 + Wp.y * q1;
    if (Wp.z != 0.0f || Wp.w != 0.0f) {          // wave-uniform (scalar W)
        f4u q2 = *(const f4u*)(xb + (uint32_t)Fp.z * NC_ + e0);
        f4u q3 = *(const f4u*)(xb + (uint32_t)Fp.w * NC_ + e0);
        ap += Wp.z * q2 + Wp.w * q3;
    }

    // ---- Phase C: combine in order, carrying ap ----
    #pragma unroll
    for (int i = 0; i < FPB_; ++i) {
        f4u a = W[i].x * v0[i] + W[i].y * v1[i];
        if (W[i].z != 0.0f || W[i].w != 0.0f) {  // wave-uniform: dropped frames only (~10%)
            f4u v2 = *(const f4u*)(xb + (uint32_t)F[i].z * NC_ + e0);
            f4u v3 = *(const f4u*)(xb + (uint32_t)F[i].w * NC_ + e0);
            a += W[i].z * v2 + W[i].w * v3;      // skipped terms are exactly 0*x
        }
        f4u r = a + (a - ap) * jv[i] + nz[i] * 0.01f + sp * 0.005f;
        __builtin_nontemporal_store(r, (f4u*)(out + (size_t)(bt0 + i) * NC_ + e0));
        ap = a;                                   // register-carried: replaces 4 Q-loads
    }
}

extern "C" void kernel_launch(void* const* d_in, const int* in_sizes, int n_in,
                              void* d_out, int out_size, void* d_ws, size_t ws_size,
                              hipStream_t stream) {
    const float* x    = (const float*)d_in[0];
    const void*  mask = d_in[1];
    const void*  keep = d_in[2];
    const float* bjit = (const float*)d_in[3];
    const float* noise = (const float*)d_in[4];
    const float* spat  = (const float*)d_in[5];
    float* out = (float*)d_out;

    char* ws = (char*)d_ws;
    int4*   wsF = (int4*)ws;                           // 218112 B
    float4* wsW = (float4*)(ws + 218112);              // 218112 B
    float*  wsJ = (float*)(ws + 436224);               // 54528 B

    prep_kernel<<<B_, 512, 0, stream>>>(mask, keep, bjit,
                                        out + XOUT_, wsF, wsW, wsJ);
    main_kernel<<<dim3(NTB_, B_), 448, 0, stream>>>(x, noise, spat, wsF, wsW, wsJ, out);
}